// Round 4
// baseline (250.191 us; speedup 1.0000x reference)
//
#include <hip/hip_runtime.h>
#include <math.h>

#define B_ 4
#define N_ 2048
#define M_ 4096

// ---- constants (fp32 copies of the reference's) ----
__constant__ float c_LO[10] = {0.0f, 0.00794435329f, 0.0158887021f, 0.0238330509f,
                               0.0317773996f, 0.0397217484f, 0.0476660972f,
                               0.0556104459f, 0.0635547947f, 0.0714991435f};
__constant__ float c_HI[10] = {0.00794435329f, 0.0158887021f, 0.0238330509f,
                               0.0317773996f, 0.0397217484f, 0.0476660972f,
                               0.0556104459f, 0.0635547947f, 0.0714991435f, 0.08f};
__constant__ float c_BW[10] = {0.16652107f, 0.21488856f, 0.37031708f, 0.55618503f,
                               0.75124664f, 0.93943357f, 1.07824539f, 1.19423112f,
                               1.55731375f, 2.34173634f};

#define R2_ 2.5e-05f   // fp32(0.005**2) — matches JAX weak-type cast
#define FAR_ 100000.0f
#define EPS_ 1e-07f

// ---------------------------------------------------------------------------
// JAX threefry2x32, key = jax.random.key(42) -> (0, 42)
__device__ inline unsigned rotl32(unsigned x, int d) { return (x << d) | (x >> (32 - d)); }

__device__ inline void threefry2x32_42(unsigned x0, unsigned x1, unsigned& o0, unsigned& o1) {
    const unsigned k0 = 0u, k1 = 42u;
    const unsigned k2 = k0 ^ k1 ^ 0x1BD11BDAu;
    const unsigned ks[3] = {k0, k1, k2};
    const int rot[2][4] = {{13, 15, 26, 6}, {17, 29, 16, 24}};
    unsigned v0 = x0 + k0;
    unsigned v1 = x1 + k1;
#pragma unroll
    for (int i = 0; i < 5; ++i) {
        const int* r = rot[i & 1];
#pragma unroll
        for (int j = 0; j < 4; ++j) {
            v0 += v1;
            v1 = rotl32(v1, r[j]);
            v1 ^= v0;
        }
        v0 += ks[(i + 1) % 3];
        v1 += ks[(i + 2) % 3] + (unsigned)(i + 1);
    }
    o0 = v0; o1 = v1;
}

__device__ inline float bits_to_uniform(unsigned bits) {
    float f = __uint_as_float((bits >> 9) | 0x3f800000u) - 1.0f;
    return fmaxf(0.0f, f);
}

__device__ inline float jax_uniform_r(int flat) {
    unsigned o0, o1;
    if (flat < 4096) {
        threefry2x32_42((unsigned)flat, (unsigned)(flat + 4096), o0, o1);
        return bits_to_uniform(o0);
    } else {
        threefry2x32_42((unsigned)(flat - 4096), (unsigned)flat, o0, o1);
        return bits_to_uniform(o1);
    }
}

// ---------------------------------------------------------------------------
// Kernel 0: pack contact points -> float4 {x,y,z,|q|^2}
__global__ void pack_contacts(const float* __restrict__ pts, float4* __restrict__ out) {
    int i = blockIdx.x * blockDim.x + threadIdx.x;
    if (i >= B_ * M_) return;
    float x = pts[(size_t)i * 3 + 0];
    float y = pts[(size_t)i * 3 + 1];
    float z = pts[(size_t)i * 3 + 2];
    out[i] = make_float4(x, y, z, x * x + y * y + z * z);
}

// ---------------------------------------------------------------------------
// Kernel 1: nearest contact per pred point.
// Grid = B * (N/8) = 1024 blocks. Block = 2 i-groups (4 i each) x 128 j-parts (32 j).
__global__ void nn_kernel(const float* __restrict__ ppts, const float4* __restrict__ cpk,
                          int* __restrict__ idx_out, float* __restrict__ d2_out) {
    int blk = blockIdx.x;                 // B * (N/8)
    int b = blk / (N_ / 8);
    int tile = blk % (N_ / 8);
    int ig = threadIdx.x & 1;             // i-group: 4 consecutive i's
    int part = threadIdx.x >> 1;          // 0..127 (j partition, ascending j)
    int i0 = tile * 8 + ig * 4;

    float ax[4], ay[4], az[4], an[4];
#pragma unroll
    for (int ii = 0; ii < 4; ++ii) {
        const float* pp = ppts + ((size_t)b * N_ + i0 + ii) * 3;
        ax[ii] = pp[0]; ay[ii] = pp[1]; az[ii] = pp[2];
        an[ii] = ax[ii] * ax[ii] + ay[ii] * ay[ii] + az[ii] * az[ii];
    }
    const float4* cb = cpk + (size_t)b * M_;

    int j0 = part * (M_ / 128);
    float best[4] = {INFINITY, INFINITY, INFINITY, INFINITY};
    int bidx[4] = {0, 0, 0, 0};
    for (int j = j0; j < j0 + (M_ / 128); ++j) {
        float4 q = cb[j];
#pragma unroll
        for (int ii = 0; ii < 4; ++ii) {
            float cross = ax[ii] * q.x + ay[ii] * q.y + az[ii] * q.z;
            float d = an[ii] + q.w - 2.0f * cross;
            d = fmaxf(d, 0.0f);
            if (d < best[ii]) { best[ii] = d; bidx[ii] = j; }   // strict <: first occurrence
        }
    }
    __shared__ float sd[128][8];
    __shared__ int si[128][8];
#pragma unroll
    for (int ii = 0; ii < 4; ++ii) {
        sd[part][ig * 4 + ii] = best[ii];
        si[part][ig * 4 + ii] = bidx[ii];
    }
    __syncthreads();
    if (threadIdx.x < 8) {
        int p2 = threadIdx.x;
        float bb = sd[0][p2];
        int bi = si[0][p2];
        for (int q = 1; q < 128; ++q) {         // ascending part == ascending j
            float dv = sd[q][p2];
            if (dv < bb) { bb = dv; bi = si[q][p2]; }
        }
        idx_out[b * N_ + tile * 8 + p2] = bi;
        d2_out[b * N_ + tile * 8 + p2] = bb;
    }
}

// ---------------------------------------------------------------------------
// Kernel 2: build P (pred control points) and G/Gs (label control points, FAR if fail)
__global__ void prep_kernel(const float* __restrict__ pred_grasps,
                            const int* __restrict__ idxw, const float* __restrict__ d2w,
                            const float* __restrict__ rot, const float* __restrict__ trans,
                            const float* __restrict__ cp, const float* __restrict__ cps,
                            float* __restrict__ Pout, float* __restrict__ Gout) {
    int i = blockIdx.x * blockDim.x + threadIdx.x;   // 0..B*N-1
    if (i >= B_ * N_) return;
    int b = i >> 11;

    const float* g = pred_grasps + (size_t)i * 16;
    float R[3][3] = {{g[0], g[1], g[2]}, {g[4], g[5], g[6]}, {g[8], g[9], g[10]}};
    float t[3] = {g[3], g[7], g[11]};

    float* P = Pout + (size_t)i * 16;
    float pn = 0.0f;
#pragma unroll
    for (int c = 0; c < 5; ++c) {
        float cx = cp[c * 3], cy = cp[c * 3 + 1], cz = cp[c * 3 + 2];
#pragma unroll
        for (int ii = 0; ii < 3; ++ii) {
            float v = R[ii][0] * cx + R[ii][1] * cy + R[ii][2] * cz + t[ii];
            P[c * 3 + ii] = v;
            pn += v * v;
        }
    }
    P[15] = pn;

    bool succ = d2w[i] < R2_;
    int j = idxw[i];
    float RL[3][3], TL[3];
    if (succ) {
        const float* rl = rot + ((size_t)b * M_ + j) * 9;
#pragma unroll
        for (int a = 0; a < 3; ++a)
#pragma unroll
            for (int bb = 0; bb < 3; ++bb) RL[a][bb] = rl[a * 3 + bb];
        const float* tl = trans + ((size_t)b * M_ + j) * 3;
        TL[0] = tl[0]; TL[1] = tl[1]; TL[2] = tl[2];
    } else {
#pragma unroll
        for (int a = 0; a < 3; ++a) {
#pragma unroll
            for (int bb = 0; bb < 3; ++bb) RL[a][bb] = FAR_;
            TL[a] = FAR_;
        }
    }

    float* G = Gout + (size_t)i * 32;
    float gn = 0.0f, gsn = 0.0f;
#pragma unroll
    for (int c = 0; c < 5; ++c) {
        float cx = cp[c * 3], cy = cp[c * 3 + 1], cz = cp[c * 3 + 2];
#pragma unroll
        for (int ii = 0; ii < 3; ++ii) {
            float v = RL[ii][0] * cx + RL[ii][1] * cy + RL[ii][2] * cz + TL[ii];
            G[c * 3 + ii] = v;
            gn += v * v;
        }
    }
    G[15] = gn;
#pragma unroll
    for (int c = 0; c < 5; ++c) {
        float cx = cps[c * 3], cy = cps[c * 3 + 1], cz = cps[c * 3 + 2];
#pragma unroll
        for (int ii = 0; ii < 3; ++ii) {
            float v = RL[ii][0] * cx + RL[ii][1] * cy + RL[ii][2] * cz + TL[ii];
            G[16 + c * 3 + ii] = v;
            gsn += v * v;
        }
    }
    G[31] = gsn;
}

// ---------------------------------------------------------------------------
// Kernel 3: ADD-S min: m[b,i] = min_j min(|P_i - G_j|^2, |P_i - Gs_j|^2)
// Grid = B * (N/16) = 512 blocks. Block = 4 i-groups (4 i each) x 64 j-parts (32 j).
// Each thread register-blocks 4 i's: one 32-float G read feeds 120 FMAs.
__global__ void adds_kernel(const float* __restrict__ Parr, const float* __restrict__ Garr,
                            float* __restrict__ mOut) {
    int blk = blockIdx.x;                  // B * (N/16)
    int b = blk / (N_ / 16);
    int tile = blk % (N_ / 16);
    int ig = threadIdx.x & 3;              // i-group: 4 consecutive i's
    int part = threadIdx.x >> 2;           // 0..63 j partitions
    int i0 = tile * 16 + ig * 4;

    const float4* P4 = reinterpret_cast<const float4*>(Parr) + ((size_t)b * N_ + i0) * 4;
    float Pv[4][16];
#pragma unroll
    for (int ii = 0; ii < 4; ++ii) {
#pragma unroll
        for (int q = 0; q < 4; ++q) {
            float4 t4 = P4[ii * 4 + q];
            Pv[ii][q * 4 + 0] = t4.x; Pv[ii][q * 4 + 1] = t4.y;
            Pv[ii][q * 4 + 2] = t4.z; Pv[ii][q * 4 + 3] = t4.w;
        }
    }

    const float4* Gb4 = reinterpret_cast<const float4*>(Garr) + (size_t)b * N_ * 8;
    float best[4] = {INFINITY, INFINITY, INFINITY, INFINITY};
    int j0 = part * (N_ / 64);
    for (int j = j0; j < j0 + (N_ / 64); ++j) {
        const float4* G4 = Gb4 + (size_t)j * 8;
        float gg[32];
#pragma unroll
        for (int q = 0; q < 8; ++q) {
            float4 t4 = G4[q];
            gg[q * 4 + 0] = t4.x; gg[q * 4 + 1] = t4.y;
            gg[q * 4 + 2] = t4.z; gg[q * 4 + 3] = t4.w;
        }
#pragma unroll
        for (int ii = 0; ii < 4; ++ii) {
            float d1 = 0.0f, d2v = 0.0f;
#pragma unroll
            for (int q = 0; q < 15; ++q) d1 += Pv[ii][q] * gg[q];
#pragma unroll
            for (int q = 0; q < 15; ++q) d2v += Pv[ii][q] * gg[16 + q];
            float s1 = Pv[ii][15] + gg[15] - 2.0f * d1;
            float s2 = Pv[ii][15] + gg[31] - 2.0f * d2v;
            best[ii] = fminf(best[ii], fminf(s1, s2));
        }
    }
    __shared__ float sm[64][16];
#pragma unroll
    for (int ii = 0; ii < 4; ++ii) sm[part][ig * 4 + ii] = best[ii];
    __syncthreads();
    if (threadIdx.x < 16) {
        float bb = sm[0][threadIdx.x];
#pragma unroll
        for (int q = 1; q < 64; ++q) bb = fminf(bb, sm[q][threadIdx.x]);
        mOut[b * N_ + tile * 16 + threadIdx.x] = bb;
    }
}

// ---------------------------------------------------------------------------
// Kernel 4: hard-negative selection, fully in-block.
// Grid = B * (N/256) = 32 blocks x 256 threads; each thread owns one n = a.
// Each block recomputes the batch's threefry priorities into LDS (pos -> INF),
// computes npos, then rank-counts with 8-wide batched LDS reads.
__global__ void sel_rank_kernel(const float* __restrict__ d2w,
                                float* __restrict__ selws) {
    int blk = blockIdx.x;
    int b = blk / (N_ / 256);
    int tile = blk % (N_ / 256);
    int tid = threadIdx.x;
    int a = tile * 256 + tid;

    __shared__ __align__(16) float pri_sh[N_];
    __shared__ int s_npos;
    if (tid == 0) s_npos = 0;
    __syncthreads();

    int local_pos = 0;
    for (int q = tid; q < N_; q += 256) {
        bool pos = d2w[b * N_ + q] < R2_;
        pri_sh[q] = pos ? INFINITY : jax_uniform_r(b * N_ + q);
        if (pos) local_pos++;
    }
    atomicAdd(&s_npos, local_pos);
    __syncthreads();

    float ra = pri_sh[a];
    int npos = s_npos;
    int kk = (npos > 0) ? npos : 2;

    int cnt = 0;
    const float4* p4 = reinterpret_cast<const float4*>(pri_sh);
    for (int q8 = 0; q8 < N_ / 4; q8 += 8) {
        float4 v[8];
#pragma unroll
        for (int k = 0; k < 8; ++k) v[k] = p4[q8 + k];   // 8 independent ds_read_b128
#pragma unroll
        for (int k = 0; k < 8; ++k) {
            int qb = (q8 + k) * 4;
            cnt += ((v[k].x < ra) || (v[k].x == ra && (qb + 0) < a)) ? 1 : 0;
            cnt += ((v[k].y < ra) || (v[k].y == ra && (qb + 1) < a)) ? 1 : 0;
            cnt += ((v[k].z < ra) || (v[k].z == ra && (qb + 2) < a)) ? 1 : 0;
            cnt += ((v[k].w < ra) || (v[k].w == ra && (qb + 3) < a)) ? 1 : 0;
        }
    }
    // positive (ra==INF): sel=1. negative: cnt == rank among negatives (positives
    // are INF and never < a finite ra); sel if rank < kk.
    float sel = (ra == INFINITY) ? 1.0f : ((cnt < kk) ? 1.0f : 0.0f);
    selws[b * N_ + a] = sel;
}

// ---------------------------------------------------------------------------
// Kernel 5: per-batch sums (bce/sel/width/adds + npos recount). B blocks x 256.
__global__ void finalize_kernel(const float* __restrict__ scores,
                                const float* __restrict__ gwh,
                                const float* __restrict__ pcw,
                                const int* __restrict__ idxw,
                                const float* __restrict__ d2w,
                                const float* __restrict__ mw,
                                const float* __restrict__ selws,
                                float* __restrict__ batch_out) {
    int b = blockIdx.x;
    int tid = threadIdx.x;
    __shared__ float wsum[4][5];

    float sum_sel = 0.0f, sum_bce = 0.0f, sum_wl = 0.0f, sum_adds = 0.0f, sum_pos = 0.0f;
    for (int n = tid; n < N_; n += 256) {
        float sc = scores[b * N_ + n];
        float pcl = fminf(fmaxf(sc, EPS_), 0.9999999f);
        bool pos = d2w[b * N_ + n] < R2_;
        float s = pos ? 1.0f : 0.0f;
        float bce = -(s * logf(pcl) + (1.0f - s) * logf(1.0f - pcl));
        float selv = selws[b * N_ + n];
        sum_sel += selv;
        sum_bce += bce * selv;
        sum_pos += s;
        if (pos) {
            int jx = idxw[b * N_ + n];
            float w = pcw[b * M_ + jx];
            float acc = 0.0f;
#pragma unroll
            for (int jb = 0; jb < 10; ++jb) {
                float x = gwh[((size_t)b * 10 + jb) * N_ + n];
                float mh = (w >= c_LO[jb] && w < c_HI[jb]) ? 1.0f : 0.0f;
                float bw = fmaxf(x, 0.0f) - x * mh + log1pf(expf(-fabsf(x)));
                acc += c_BW[jb] * bw;
            }
            sum_wl += acc * 0.1f;
            float mv = mw[b * N_ + n];
            sum_adds += sc * sqrtf(fmaxf(mv, 0.0f) + 1e-12f);
        }
    }

    // deterministic reduce: wave shuffle + per-wave LDS + thread-0 combine
    float v0 = sum_sel, v1 = sum_bce, v2 = sum_wl, v3 = sum_adds, v4 = sum_pos;
#pragma unroll
    for (int off = 32; off > 0; off >>= 1) {
        v0 += __shfl_down(v0, off);
        v1 += __shfl_down(v1, off);
        v2 += __shfl_down(v2, off);
        v3 += __shfl_down(v3, off);
        v4 += __shfl_down(v4, off);
    }
    int wv = tid >> 6, lane = tid & 63;
    if (lane == 0) {
        wsum[wv][0] = v0; wsum[wv][1] = v1; wsum[wv][2] = v2; wsum[wv][3] = v3; wsum[wv][4] = v4;
    }
    __syncthreads();
    if (tid == 0) {
        float t0 = 0, t1 = 0, t2 = 0, t3 = 0, t4 = 0;
#pragma unroll
        for (int w = 0; w < 4; ++w) {
            t0 += wsum[w][0]; t1 += wsum[w][1]; t2 += wsum[w][2]; t3 += wsum[w][3]; t4 += wsum[w][4];
        }
        float piv = fmaxf(t4, 1.0f);                 // pos_in_view
        batch_out[b * 3 + 0] = t1 / fmaxf(t0, 1.0f);
        batch_out[b * 3 + 1] = t2 / piv;
        batch_out[b * 3 + 2] = t3 / piv;
    }
}

// ---------------------------------------------------------------------------
// Kernel 6: combine batches -> 4 outputs
__global__ void combine_kernel(const float* __restrict__ bv, float* __restrict__ out) {
    if (blockIdx.x == 0 && threadIdx.x == 0) {
        float bin = 0, wid = 0, ad = 0;
#pragma unroll
        for (int b = 0; b < B_; ++b) {
            bin += bv[b * 3 + 0];
            wid += bv[b * 3 + 1];
            ad += bv[b * 3 + 2];
        }
        bin *= 0.25f; wid *= 0.25f; ad *= 0.25f;
        out[0] = bin + wid + 3.0f * ad;
        out[1] = bin;
        out[2] = wid;
        out[3] = ad;
    }
}

// ---------------------------------------------------------------------------
extern "C" void kernel_launch(void* const* d_in, const int* in_sizes, int n_in,
                              void* d_out, int out_size, void* d_ws, size_t ws_size,
                              hipStream_t stream) {
    const float* pred_grasps = (const float*)d_in[0];   // (4,2048,4,4)
    const float* pred_scores = (const float*)d_in[1];   // (4,2048,1)
    const float* pred_points = (const float*)d_in[2];   // (4,2048,3)
    const float* gwh         = (const float*)d_in[3];   // (4,10,2048)
    const float* pcp         = (const float*)d_in[4];   // (4,4096,3)
    const float* pcw         = (const float*)d_in[5];   // (4,4096)
    const float* pcr         = (const float*)d_in[6];   // (4,4096,3,3)
    const float* pct         = (const float*)d_in[7];   // (4,4096,3)
    const float* cp          = (const float*)d_in[8];   // (1,5,3)
    const float* cps         = (const float*)d_in[9];   // (1,5,3)
    (void)in_sizes; (void)n_in; (void)out_size; (void)ws_size;

    float* ws = (float*)d_ws;
    float4* cpack = (float4*)ws;                        //  65536 floats (dead after nn)
    int*   idxw = (int*)(ws + 65536);                   //   8192
    float* d2w  = ws + 65536 + 8192;                    //   8192
    float* Pw   = ws + 65536 + 16384;                   // 131072
    float* Gw   = Pw + 131072;                          // 262144
    float* mw   = Gw + 262144;                          //   8192
    float* bv   = mw + 8192;                            //     16 (12 used)
    // selection output aliases the dead cpack region (written after nn_kernel)
    float* selws = ws;                                  //   8192
    float* outp = (float*)d_out;

    hipLaunchKernelGGL(pack_contacts, dim3((B_ * M_ + 255) / 256), dim3(256), 0, stream,
                       pcp, cpack);
    hipLaunchKernelGGL(nn_kernel, dim3(B_ * (N_ / 8)), dim3(256), 0, stream,
                       pred_points, cpack, idxw, d2w);
    hipLaunchKernelGGL(prep_kernel, dim3((B_ * N_ + 255) / 256), dim3(256), 0, stream,
                       pred_grasps, idxw, d2w, pcr, pct, cp, cps, Pw, Gw);
    hipLaunchKernelGGL(adds_kernel, dim3(B_ * (N_ / 16)), dim3(256), 0, stream,
                       Pw, Gw, mw);
    hipLaunchKernelGGL(sel_rank_kernel, dim3(B_ * (N_ / 256)), dim3(256), 0, stream,
                       d2w, selws);
    hipLaunchKernelGGL(finalize_kernel, dim3(B_), dim3(256), 0, stream,
                       pred_scores, gwh, pcw, idxw, d2w, mw, selws, bv);
    hipLaunchKernelGGL(combine_kernel, dim3(1), dim3(64), 0, stream, bv, outp);
}

// Round 5
// 193.985 us; speedup vs baseline: 1.2897x; 1.2897x over previous
//
#include <hip/hip_runtime.h>
#include <math.h>

#define B_ 4
#define N_ 2048
#define M_ 4096

// ---- constants (fp32 copies of the reference's) ----
__constant__ float c_LO[10] = {0.0f, 0.00794435329f, 0.0158887021f, 0.0238330509f,
                               0.0317773996f, 0.0397217484f, 0.0476660972f,
                               0.0556104459f, 0.0635547947f, 0.0714991435f};
__constant__ float c_HI[10] = {0.00794435329f, 0.0158887021f, 0.0238330509f,
                               0.0317773996f, 0.0397217484f, 0.0476660972f,
                               0.0556104459f, 0.0635547947f, 0.0714991435f, 0.08f};
__constant__ float c_BW[10] = {0.16652107f, 0.21488856f, 0.37031708f, 0.55618503f,
                               0.75124664f, 0.93943357f, 1.07824539f, 1.19423112f,
                               1.55731375f, 2.34173634f};

#define R2_ 2.5e-05f   // fp32(0.005**2) — matches JAX weak-type cast
#define FAR_ 100000.0f
#define EPS_ 1e-07f

// ---------------------------------------------------------------------------
// JAX threefry2x32, key = jax.random.key(42) -> (0, 42)
__device__ inline unsigned rotl32(unsigned x, int d) { return (x << d) | (x >> (32 - d)); }

__device__ inline void threefry2x32_42(unsigned x0, unsigned x1, unsigned& o0, unsigned& o1) {
    const unsigned k0 = 0u, k1 = 42u;
    const unsigned k2 = k0 ^ k1 ^ 0x1BD11BDAu;
    const unsigned ks[3] = {k0, k1, k2};
    const int rot[2][4] = {{13, 15, 26, 6}, {17, 29, 16, 24}};
    unsigned v0 = x0 + k0;
    unsigned v1 = x1 + k1;
#pragma unroll
    for (int i = 0; i < 5; ++i) {
        const int* r = rot[i & 1];
#pragma unroll
        for (int j = 0; j < 4; ++j) {
            v0 += v1;
            v1 = rotl32(v1, r[j]);
            v1 ^= v0;
        }
        v0 += ks[(i + 1) % 3];
        v1 += ks[(i + 2) % 3] + (unsigned)(i + 1);
    }
    o0 = v0; o1 = v1;
}

__device__ inline float bits_to_uniform(unsigned bits) {
    float f = __uint_as_float((bits >> 9) | 0x3f800000u) - 1.0f;
    return fmaxf(0.0f, f);
}

__device__ inline float jax_uniform_r(int flat) {
    unsigned o0, o1;
    if (flat < 4096) {
        threefry2x32_42((unsigned)flat, (unsigned)(flat + 4096), o0, o1);
        return bits_to_uniform(o0);
    } else {
        threefry2x32_42((unsigned)(flat - 4096), (unsigned)flat, o0, o1);
        return bits_to_uniform(o1);
    }
}

// ---------------------------------------------------------------------------
// K1: fused pack + NN + prep.
// Grid = B*(N/8) = 1024 blocks, 256 threads.
// Stage all M contact points (+norm) into 64KB LDS, argmin over M with
// interleaved j-assignment (bank-conflict-free), then 8 winner threads build
// P/G/Gs rows inline (the old prep_kernel logic).
__global__ __launch_bounds__(256) void nn_prep_kernel(
        const float* __restrict__ ppts, const float* __restrict__ pcp,
        const float* __restrict__ pred_grasps,
        const float* __restrict__ rot, const float* __restrict__ trans,
        const float* __restrict__ cp, const float* __restrict__ cps,
        int* __restrict__ idx_out, float* __restrict__ d2_out,
        float* __restrict__ Pout, float* __restrict__ Gout) {
    int blk = blockIdx.x;
    int b = blk / (N_ / 8);
    int tile = blk % (N_ / 8);
    int tid = threadIdx.x;

    __shared__ __align__(16) char smem[65536];
    float4* spts = (float4*)smem;

    // stage: pack contact points with norm into LDS (coalesced global reads)
    const float* pb = pcp + (size_t)b * M_ * 3;
    for (int t = tid; t < M_; t += 256) {
        float x = pb[t * 3 + 0];
        float y = pb[t * 3 + 1];
        float z = pb[t * 3 + 2];
        spts[t] = make_float4(x, y, z, x * x + y * y + z * z);
    }
    __syncthreads();

    int ig = tid & 1;             // i-group: 4 consecutive i's
    int part = tid >> 1;          // 0..127
    int i0 = tile * 8 + ig * 4;

    float ax[4], ay[4], az[4], an[4];
#pragma unroll
    for (int ii = 0; ii < 4; ++ii) {
        const float* pp = ppts + ((size_t)b * N_ + i0 + ii) * 3;
        ax[ii] = pp[0]; ay[ii] = pp[1]; az[ii] = pp[2];
        an[ii] = ax[ii] * ax[ii] + ay[ii] * ay[ii] + az[ii] * az[ii];
    }

    // j interleave: part p owns j = p + jj*128 (lanes' LDS addrs 16B apart)
    float best[4] = {INFINITY, INFINITY, INFINITY, INFINITY};
    int bidx[4] = {0, 0, 0, 0};
    for (int jj = 0; jj < 32; jj += 4) {
        float4 q4[4];
#pragma unroll
        for (int k = 0; k < 4; ++k) q4[k] = spts[part + (jj + k) * 128];
#pragma unroll
        for (int k = 0; k < 4; ++k) {
            int j = part + (jj + k) * 128;
#pragma unroll
            for (int ii = 0; ii < 4; ++ii) {
                float cross = ax[ii] * q4[k].x + ay[ii] * q4[k].y + az[ii] * q4[k].z;
                float d = an[ii] + q4[k].w - 2.0f * cross;
                d = fmaxf(d, 0.0f);
                // strict <: earliest-visited (= smallest j in this thread's set)
                if (d < best[ii]) { best[ii] = d; bidx[ii] = j; }
            }
        }
    }

    __syncthreads();    // all LDS point reads done; reuse smem for reduction
    float* sd = (float*)smem;             // [8][128]
    int* si = (int*)(smem + 4096);        // [8][128]
#pragma unroll
    for (int ii = 0; ii < 4; ++ii) {
        sd[(ig * 4 + ii) * 128 + part] = best[ii];
        si[(ig * 4 + ii) * 128 + part] = bidx[ii];
    }
    __syncthreads();

    if (tid < 8) {
        int n = tile * 8 + tid;
        float bb = INFINITY;
        int bi = 0x7fffffff;
        for (int p = 0; p < 128; ++p) {
            float dv = sd[tid * 128 + p];
            int iv = si[tid * 128 + p];
            // explicit tie-break on smallest j (interleaved sets break j-order)
            if (dv < bb || (dv == bb && iv < bi)) { bb = dv; bi = iv; }
        }
        idx_out[b * N_ + n] = bi;
        d2_out[b * N_ + n] = bb;

        // ---- inline prep for this n ----
        size_t i = (size_t)b * N_ + n;
        const float* g = pred_grasps + i * 16;
        float R[3][3] = {{g[0], g[1], g[2]}, {g[4], g[5], g[6]}, {g[8], g[9], g[10]}};
        float t[3] = {g[3], g[7], g[11]};

        float* P = Pout + i * 16;
        float pn = 0.0f;
#pragma unroll
        for (int c = 0; c < 5; ++c) {
            float cx = cp[c * 3], cy = cp[c * 3 + 1], cz = cp[c * 3 + 2];
#pragma unroll
            for (int kk = 0; kk < 3; ++kk) {
                float v = R[kk][0] * cx + R[kk][1] * cy + R[kk][2] * cz + t[kk];
                P[c * 3 + kk] = v;
                pn += v * v;
            }
        }
        P[15] = pn;

        bool succ = bb < R2_;
        float RL[3][3], TL[3];
        if (succ) {
            const float* rl = rot + ((size_t)b * M_ + bi) * 9;
#pragma unroll
            for (int a = 0; a < 3; ++a)
#pragma unroll
                for (int c2 = 0; c2 < 3; ++c2) RL[a][c2] = rl[a * 3 + c2];
            const float* tl = trans + ((size_t)b * M_ + bi) * 3;
            TL[0] = tl[0]; TL[1] = tl[1]; TL[2] = tl[2];
        } else {
#pragma unroll
            for (int a = 0; a < 3; ++a) {
#pragma unroll
                for (int c2 = 0; c2 < 3; ++c2) RL[a][c2] = FAR_;
                TL[a] = FAR_;
            }
        }

        float* G = Gout + i * 32;
        float gn = 0.0f, gsn = 0.0f;
#pragma unroll
        for (int c = 0; c < 5; ++c) {
            float cx = cp[c * 3], cy = cp[c * 3 + 1], cz = cp[c * 3 + 2];
#pragma unroll
            for (int kk = 0; kk < 3; ++kk) {
                float v = RL[kk][0] * cx + RL[kk][1] * cy + RL[kk][2] * cz + TL[kk];
                G[c * 3 + kk] = v;
                gn += v * v;
            }
        }
        G[15] = gn;
#pragma unroll
        for (int c = 0; c < 5; ++c) {
            float cx = cps[c * 3], cy = cps[c * 3 + 1], cz = cps[c * 3 + 2];
#pragma unroll
            for (int kk = 0; kk < 3; ++kk) {
                float v = RL[kk][0] * cx + RL[kk][1] * cy + RL[kk][2] * cz + TL[kk];
                G[16 + c * 3 + kk] = v;
                gsn += v * v;
            }
        }
        G[31] = gsn;
    }
}

// ---------------------------------------------------------------------------
// K2: hard-negative selection.
// Grid = B*(N/16) = 512 blocks; block = 16 n-owners x 16 partitions (128 el).
// In-block threefry priorities + npos; rank-count with stride-16 interleaved
// float4 LDS reads (conflict-free) and 4-wide batches (16 regs, no spill).
// Block 0 also zeroes the finalize done-counter (runs before finalize).
__global__ __launch_bounds__(256) void rank_kernel(const float* __restrict__ d2w,
                                                   float* __restrict__ selws,
                                                   int* __restrict__ done_cnt) {
    if (blockIdx.x == 0 && threadIdx.x == 0) *done_cnt = 0;
    int blk = blockIdx.x;
    int b = blk / (N_ / 16);
    int tile = blk % (N_ / 16);
    int tid = threadIdx.x;
    int n_local = tid & 15;
    int part = tid >> 4;              // 0..15

    __shared__ __align__(16) float pri[N_];
    __shared__ int cnt_sh[16][17];
    __shared__ int s_npos;
    if (tid == 0) s_npos = 0;
    __syncthreads();

    int lp = 0;
    for (int q = tid; q < N_; q += 256) {
        bool pos = d2w[b * N_ + q] < R2_;
        pri[q] = pos ? INFINITY : jax_uniform_r(b * N_ + q);
        if (pos) lp++;
    }
    atomicAdd(&s_npos, lp);
    __syncthreads();

    int n = tile * 16 + n_local;
    float ra = pri[n];

    int cnt = 0;
    const float4* p4 = reinterpret_cast<const float4*>(pri);
    for (int o = 0; o < 8; ++o) {
        float4 v[4];
#pragma unroll
        for (int k = 0; k < 4; ++k) v[k] = p4[part + (o * 4 + k) * 16];
#pragma unroll
        for (int k = 0; k < 4; ++k) {
            int qb = (part + (o * 4 + k) * 16) * 4;
            cnt += ((v[k].x < ra) || (v[k].x == ra && (qb + 0) < n)) ? 1 : 0;
            cnt += ((v[k].y < ra) || (v[k].y == ra && (qb + 1) < n)) ? 1 : 0;
            cnt += ((v[k].z < ra) || (v[k].z == ra && (qb + 2) < n)) ? 1 : 0;
            cnt += ((v[k].w < ra) || (v[k].w == ra && (qb + 3) < n)) ? 1 : 0;
        }
    }
    cnt_sh[part][n_local] = cnt;
    __syncthreads();

    if (tid < 16) {
        int tot = 0;
#pragma unroll
        for (int p = 0; p < 16; ++p) tot += cnt_sh[p][tid];
        int npos = s_npos;
        int kk = (npos > 0) ? npos : 2;
        int n2 = tile * 16 + tid;
        float r2 = pri[n2];
        selws[b * N_ + n2] = (r2 == INFINITY) ? 1.0f : ((tot < kk) ? 1.0f : 0.0f);
    }
}

// ---------------------------------------------------------------------------
// K3: ADD-S min. Grid = B*(N/16) = 512 blocks (2/CU).
// Block = 4 i-groups (4 i each) x 64 j-parts (32 j). gg loaded in two
// 16-float halves to keep live regs ~100; launch_bounds(256,2) forbids spill.
__global__ __launch_bounds__(256, 2) void adds_kernel(const float* __restrict__ Parr,
                                                      const float* __restrict__ Garr,
                                                      float* __restrict__ mOut) {
    int blk = blockIdx.x;
    int b = blk / (N_ / 16);
    int tile = blk % (N_ / 16);
    int ig = threadIdx.x & 3;
    int part = threadIdx.x >> 2;           // 0..63
    int i0 = tile * 16 + ig * 4;

    const float4* P4 = reinterpret_cast<const float4*>(Parr) + ((size_t)b * N_ + i0) * 4;
    float Pv[4][16];
#pragma unroll
    for (int ii = 0; ii < 4; ++ii) {
#pragma unroll
        for (int q = 0; q < 4; ++q) {
            float4 t4 = P4[ii * 4 + q];
            Pv[ii][q * 4 + 0] = t4.x; Pv[ii][q * 4 + 1] = t4.y;
            Pv[ii][q * 4 + 2] = t4.z; Pv[ii][q * 4 + 3] = t4.w;
        }
    }

    const float4* Gb4 = reinterpret_cast<const float4*>(Garr) + (size_t)b * N_ * 8;
    float best[4] = {INFINITY, INFINITY, INFINITY, INFINITY};
    int j0 = part * (N_ / 64);
    for (int j = j0; j < j0 + (N_ / 64); ++j) {
        const float4* G4 = Gb4 + (size_t)j * 8;
        float gg[16];
        // half 1: G
#pragma unroll
        for (int q = 0; q < 4; ++q) {
            float4 t4 = G4[q];
            gg[q * 4 + 0] = t4.x; gg[q * 4 + 1] = t4.y;
            gg[q * 4 + 2] = t4.z; gg[q * 4 + 3] = t4.w;
        }
        {
            float d[4] = {0.0f, 0.0f, 0.0f, 0.0f};
#pragma unroll
            for (int q = 0; q < 15; ++q)
#pragma unroll
                for (int ii = 0; ii < 4; ++ii) d[ii] += Pv[ii][q] * gg[q];
#pragma unroll
            for (int ii = 0; ii < 4; ++ii) {
                float s = Pv[ii][15] + gg[15] - 2.0f * d[ii];
                best[ii] = fminf(best[ii], s);
            }
        }
        // half 2: Gs
#pragma unroll
        for (int q = 0; q < 4; ++q) {
            float4 t4 = G4[4 + q];
            gg[q * 4 + 0] = t4.x; gg[q * 4 + 1] = t4.y;
            gg[q * 4 + 2] = t4.z; gg[q * 4 + 3] = t4.w;
        }
        {
            float d[4] = {0.0f, 0.0f, 0.0f, 0.0f};
#pragma unroll
            for (int q = 0; q < 15; ++q)
#pragma unroll
                for (int ii = 0; ii < 4; ++ii) d[ii] += Pv[ii][q] * gg[q];
#pragma unroll
            for (int ii = 0; ii < 4; ++ii) {
                float s = Pv[ii][15] + gg[15] - 2.0f * d[ii];
                best[ii] = fminf(best[ii], s);
            }
        }
    }
    __shared__ float sm[64][17];
#pragma unroll
    for (int ii = 0; ii < 4; ++ii) sm[part][ig * 4 + ii] = best[ii];
    __syncthreads();
    if (threadIdx.x < 16) {
        float bb = sm[0][threadIdx.x];
#pragma unroll
        for (int q = 1; q < 64; ++q) bb = fminf(bb, sm[q][threadIdx.x]);
        mOut[b * N_ + tile * 16 + threadIdx.x] = bb;
    }
}

// ---------------------------------------------------------------------------
// K4: per-batch sums + last-block combine (no separate combine dispatch).
__global__ __launch_bounds__(256) void finalize_kernel(
        const float* __restrict__ scores, const float* __restrict__ gwh,
        const float* __restrict__ pcw, const int* __restrict__ idxw,
        const float* __restrict__ d2w, const float* __restrict__ mw,
        const float* __restrict__ selws,
        float* __restrict__ batch_out, int* __restrict__ done_cnt,
        float* __restrict__ out) {
    int b = blockIdx.x;
    int tid = threadIdx.x;
    __shared__ float wsum[4][5];

    float sum_sel = 0.0f, sum_bce = 0.0f, sum_wl = 0.0f, sum_adds = 0.0f, sum_pos = 0.0f;
    for (int n = tid; n < N_; n += 256) {
        float sc = scores[b * N_ + n];
        float pcl = fminf(fmaxf(sc, EPS_), 0.9999999f);
        bool pos = d2w[b * N_ + n] < R2_;
        float s = pos ? 1.0f : 0.0f;
        float bce = -(s * logf(pcl) + (1.0f - s) * logf(1.0f - pcl));
        float selv = selws[b * N_ + n];
        sum_sel += selv;
        sum_bce += bce * selv;
        sum_pos += s;
        if (pos) {
            int jx = idxw[b * N_ + n];
            float w = pcw[b * M_ + jx];
            float acc = 0.0f;
#pragma unroll
            for (int jb = 0; jb < 10; ++jb) {
                float x = gwh[((size_t)b * 10 + jb) * N_ + n];
                float mh = (w >= c_LO[jb] && w < c_HI[jb]) ? 1.0f : 0.0f;
                float bw = fmaxf(x, 0.0f) - x * mh + log1pf(expf(-fabsf(x)));
                acc += c_BW[jb] * bw;
            }
            sum_wl += acc * 0.1f;
            float mv = mw[b * N_ + n];
            sum_adds += sc * sqrtf(fmaxf(mv, 0.0f) + 1e-12f);
        }
    }

    // deterministic reduce: wave shuffle + per-wave LDS + thread-0 combine
    float v0 = sum_sel, v1 = sum_bce, v2 = sum_wl, v3 = sum_adds, v4 = sum_pos;
#pragma unroll
    for (int off = 32; off > 0; off >>= 1) {
        v0 += __shfl_down(v0, off);
        v1 += __shfl_down(v1, off);
        v2 += __shfl_down(v2, off);
        v3 += __shfl_down(v3, off);
        v4 += __shfl_down(v4, off);
    }
    int wv = tid >> 6, lane = tid & 63;
    if (lane == 0) {
        wsum[wv][0] = v0; wsum[wv][1] = v1; wsum[wv][2] = v2; wsum[wv][3] = v3; wsum[wv][4] = v4;
    }
    __syncthreads();
    if (tid == 0) {
        float t0 = 0, t1 = 0, t2 = 0, t3 = 0, t4 = 0;
#pragma unroll
        for (int w = 0; w < 4; ++w) {
            t0 += wsum[w][0]; t1 += wsum[w][1]; t2 += wsum[w][2]; t3 += wsum[w][3]; t4 += wsum[w][4];
        }
        float piv = fmaxf(t4, 1.0f);                 // pos_in_view
        batch_out[b * 3 + 0] = t1 / fmaxf(t0, 1.0f);
        batch_out[b * 3 + 1] = t2 / piv;
        batch_out[b * 3 + 2] = t3 / piv;
        __threadfence();
        int old = atomicAdd(done_cnt, 1);
        if (old == B_ - 1) {
            __threadfence();
            float bin = 0, wid = 0, ad = 0;
#pragma unroll
            for (int bb2 = 0; bb2 < B_; ++bb2) {
                bin += batch_out[bb2 * 3 + 0];
                wid += batch_out[bb2 * 3 + 1];
                ad += batch_out[bb2 * 3 + 2];
            }
            bin *= 0.25f; wid *= 0.25f; ad *= 0.25f;
            out[0] = bin + wid + 3.0f * ad;
            out[1] = bin;
            out[2] = wid;
            out[3] = ad;
        }
    }
}

// ---------------------------------------------------------------------------
extern "C" void kernel_launch(void* const* d_in, const int* in_sizes, int n_in,
                              void* d_out, int out_size, void* d_ws, size_t ws_size,
                              hipStream_t stream) {
    const float* pred_grasps = (const float*)d_in[0];   // (4,2048,4,4)
    const float* pred_scores = (const float*)d_in[1];   // (4,2048,1)
    const float* pred_points = (const float*)d_in[2];   // (4,2048,3)
    const float* gwh         = (const float*)d_in[3];   // (4,10,2048)
    const float* pcp         = (const float*)d_in[4];   // (4,4096,3)
    const float* pcw         = (const float*)d_in[5];   // (4,4096)
    const float* pcr         = (const float*)d_in[6];   // (4,4096,3,3)
    const float* pct         = (const float*)d_in[7];   // (4,4096,3)
    const float* cp          = (const float*)d_in[8];   // (1,5,3)
    const float* cps         = (const float*)d_in[9];   // (1,5,3)
    (void)in_sizes; (void)n_in; (void)out_size; (void)ws_size;

    float* ws = (float*)d_ws;
    int*   idxw  = (int*)ws;                            //   8192
    float* d2w   = ws + 8192;                           //   8192
    float* Pw    = ws + 16384;                          // 131072
    float* Gw    = Pw + 131072;                         // 262144
    float* mw    = Gw + 262144;                         //   8192
    float* selws = mw + 8192;                           //   8192
    float* bv    = selws + 8192;                        //     12
    int*   done  = (int*)(bv + 12);                     //      1
    float* outp  = (float*)d_out;

    hipLaunchKernelGGL(nn_prep_kernel, dim3(B_ * (N_ / 8)), dim3(256), 0, stream,
                       pred_points, pcp, pred_grasps, pcr, pct, cp, cps,
                       idxw, d2w, Pw, Gw);
    hipLaunchKernelGGL(rank_kernel, dim3(B_ * (N_ / 16)), dim3(256), 0, stream,
                       d2w, selws, done);
    hipLaunchKernelGGL(adds_kernel, dim3(B_ * (N_ / 16)), dim3(256), 0, stream,
                       Pw, Gw, mw);
    hipLaunchKernelGGL(finalize_kernel, dim3(B_), dim3(256), 0, stream,
                       pred_scores, gwh, pcw, idxw, d2w, mw, selws, bv, done, outp);
}

// Round 6
// 162.773 us; speedup vs baseline: 1.5371x; 1.1918x over previous
//
#include <hip/hip_runtime.h>
#include <math.h>

#define B_ 4
#define N_ 2048
#define M_ 4096

// ---- constants (fp32 copies of the reference's) ----
__constant__ float c_LO[10] = {0.0f, 0.00794435329f, 0.0158887021f, 0.0238330509f,
                               0.0317773996f, 0.0397217484f, 0.0476660972f,
                               0.0556104459f, 0.0635547947f, 0.0714991435f};
__constant__ float c_HI[10] = {0.00794435329f, 0.0158887021f, 0.0238330509f,
                               0.0317773996f, 0.0397217484f, 0.0476660972f,
                               0.0556104459f, 0.0635547947f, 0.0714991435f, 0.08f};
__constant__ float c_BW[10] = {0.16652107f, 0.21488856f, 0.37031708f, 0.55618503f,
                               0.75124664f, 0.93943357f, 1.07824539f, 1.19423112f,
                               1.55731375f, 2.34173634f};

#define R2_ 2.5e-05f   // fp32(0.005**2) — matches JAX weak-type cast
#define FAR_ 100000.0f
#define EPS_ 1e-07f

// ---------------------------------------------------------------------------
// JAX threefry2x32, key = jax.random.key(42) -> (0, 42)
__device__ inline unsigned rotl32(unsigned x, int d) { return (x << d) | (x >> (32 - d)); }

__device__ inline void threefry2x32_42(unsigned x0, unsigned x1, unsigned& o0, unsigned& o1) {
    const unsigned k0 = 0u, k1 = 42u;
    const unsigned k2 = k0 ^ k1 ^ 0x1BD11BDAu;
    const unsigned ks[3] = {k0, k1, k2};
    const int rot[2][4] = {{13, 15, 26, 6}, {17, 29, 16, 24}};
    unsigned v0 = x0 + k0;
    unsigned v1 = x1 + k1;
#pragma unroll
    for (int i = 0; i < 5; ++i) {
        const int* r = rot[i & 1];
#pragma unroll
        for (int j = 0; j < 4; ++j) {
            v0 += v1;
            v1 = rotl32(v1, r[j]);
            v1 ^= v0;
        }
        v0 += ks[(i + 1) % 3];
        v1 += ks[(i + 2) % 3] + (unsigned)(i + 1);
    }
    o0 = v0; o1 = v1;
}

__device__ inline float bits_to_uniform(unsigned bits) {
    float f = __uint_as_float((bits >> 9) | 0x3f800000u) - 1.0f;
    return fmaxf(0.0f, f);
}

__device__ inline float jax_uniform_r(int flat) {
    unsigned o0, o1;
    if (flat < 4096) {
        threefry2x32_42((unsigned)flat, (unsigned)(flat + 4096), o0, o1);
        return bits_to_uniform(o0);
    } else {
        threefry2x32_42((unsigned)(flat - 4096), (unsigned)flat, o0, o1);
        return bits_to_uniform(o1);
    }
}

// ---------------------------------------------------------------------------
// K1: fused NN + prep. Grid = B*(N/8) = 1024 blocks (4 blocks/CU, 16 waves/CU).
// Block = 2 i-groups (4 i each) x 128 j-parts; part p owns 4-point groups
// {p + g*128 : g<8} read as 3x float4 (coalesced), norms computed inline.
__global__ __launch_bounds__(256, 4) void nn_prep_kernel(
        const float* __restrict__ ppts, const float* __restrict__ pcp,
        const float* __restrict__ pred_grasps,
        const float* __restrict__ rot, const float* __restrict__ trans,
        const float* __restrict__ cp, const float* __restrict__ cps,
        int* __restrict__ idx_out, float* __restrict__ d2_out,
        float* __restrict__ Pout, float* __restrict__ Gout) {
    int blk = blockIdx.x;
    int b = blk / (N_ / 8);
    int tile = blk % (N_ / 8);
    int tid = threadIdx.x;
    int ig = tid & 1;             // i-group: 4 consecutive i's
    int part = tid >> 1;          // 0..127
    int i0 = tile * 8 + ig * 4;

    float ax[4], ay[4], az[4], an[4];
#pragma unroll
    for (int ii = 0; ii < 4; ++ii) {
        const float* pp = ppts + ((size_t)b * N_ + i0 + ii) * 3;
        ax[ii] = pp[0]; ay[ii] = pp[1]; az[ii] = pp[2];
        an[ii] = ax[ii] * ax[ii] + ay[ii] * ay[ii] + az[ii] * az[ii];
    }

    const float4* pb4 = reinterpret_cast<const float4*>(pcp + (size_t)b * M_ * 3);
    float best[4] = {INFINITY, INFINITY, INFINITY, INFINITY};
    int bidx[4] = {0, 0, 0, 0};
    for (int g = 0; g < 8; ++g) {
        int grp = g * 128 + part;            // group of 4 contact points
        float4 q0 = pb4[grp * 3 + 0];
        float4 q1 = pb4[grp * 3 + 1];
        float4 q2 = pb4[grp * 3 + 2];
        float px[4] = {q0.x, q0.w, q1.z, q2.y};
        float py[4] = {q0.y, q1.x, q1.w, q2.z};
        float pz[4] = {q0.z, q1.y, q2.x, q2.w};
#pragma unroll
        for (int k = 0; k < 4; ++k) {
            float bn = px[k] * px[k] + py[k] * py[k] + pz[k] * pz[k];
            int j = grp * 4 + k;             // ascending within thread (g,k asc)
#pragma unroll
            for (int ii = 0; ii < 4; ++ii) {
                float cross = ax[ii] * px[k] + ay[ii] * py[k] + az[ii] * pz[k];
                float d = an[ii] + bn - 2.0f * cross;
                d = fmaxf(d, 0.0f);
                if (d < best[ii]) { best[ii] = d; bidx[ii] = j; }  // first occurrence
            }
        }
    }

    __shared__ float sd[8][128];
    __shared__ int si[8][128];
#pragma unroll
    for (int ii = 0; ii < 4; ++ii) {
        sd[ig * 4 + ii][part] = best[ii];
        si[ig * 4 + ii][part] = bidx[ii];
    }
    __syncthreads();

    if (tid < 8) {
        int n = tile * 8 + tid;
        float bb = INFINITY;
        int bi = 0x7fffffff;
        for (int p = 0; p < 128; ++p) {
            float dv = sd[tid][p];
            int iv = si[tid][p];
            // explicit tie-break on smallest j (interleaved part sets)
            if (dv < bb || (dv == bb && iv < bi)) { bb = dv; bi = iv; }
        }
        idx_out[b * N_ + n] = bi;
        d2_out[b * N_ + n] = bb;

        // ---- inline prep for this n ----
        size_t i = (size_t)b * N_ + n;
        const float* g = pred_grasps + i * 16;
        float R[3][3] = {{g[0], g[1], g[2]}, {g[4], g[5], g[6]}, {g[8], g[9], g[10]}};
        float t[3] = {g[3], g[7], g[11]};

        float* P = Pout + i * 16;
        float pn = 0.0f;
#pragma unroll
        for (int c = 0; c < 5; ++c) {
            float cx = cp[c * 3], cy = cp[c * 3 + 1], cz = cp[c * 3 + 2];
#pragma unroll
            for (int kk = 0; kk < 3; ++kk) {
                float v = R[kk][0] * cx + R[kk][1] * cy + R[kk][2] * cz + t[kk];
                P[c * 3 + kk] = v;
                pn += v * v;
            }
        }
        P[15] = pn;

        bool succ = bb < R2_;
        float RL[3][3], TL[3];
        if (succ) {
            const float* rl = rot + ((size_t)b * M_ + bi) * 9;
#pragma unroll
            for (int a = 0; a < 3; ++a)
#pragma unroll
                for (int c2 = 0; c2 < 3; ++c2) RL[a][c2] = rl[a * 3 + c2];
            const float* tl = trans + ((size_t)b * M_ + bi) * 3;
            TL[0] = tl[0]; TL[1] = tl[1]; TL[2] = tl[2];
        } else {
#pragma unroll
            for (int a = 0; a < 3; ++a) {
#pragma unroll
                for (int c2 = 0; c2 < 3; ++c2) RL[a][c2] = FAR_;
                TL[a] = FAR_;
            }
        }

        float* G = Gout + i * 32;
        float gn = 0.0f, gsn = 0.0f;
#pragma unroll
        for (int c = 0; c < 5; ++c) {
            float cx = cp[c * 3], cy = cp[c * 3 + 1], cz = cp[c * 3 + 2];
#pragma unroll
            for (int kk = 0; kk < 3; ++kk) {
                float v = RL[kk][0] * cx + RL[kk][1] * cy + RL[kk][2] * cz + TL[kk];
                G[c * 3 + kk] = v;
                gn += v * v;
            }
        }
        G[15] = gn;
#pragma unroll
        for (int c = 0; c < 5; ++c) {
            float cx = cps[c * 3], cy = cps[c * 3 + 1], cz = cps[c * 3 + 2];
#pragma unroll
            for (int kk = 0; kk < 3; ++kk) {
                float v = RL[kk][0] * cx + RL[kk][1] * cy + RL[kk][2] * cz + TL[kk];
                G[16 + c * 3 + kk] = v;
                gsn += v * v;
            }
        }
        G[31] = gsn;
    }
}

// ---------------------------------------------------------------------------
// K2: hard-negative selection (unchanged structure from R5 — was off the
// hot list). Also zeroes the finalize done-counter.
__global__ __launch_bounds__(256) void rank_kernel(const float* __restrict__ d2w,
                                                   float* __restrict__ selws,
                                                   int* __restrict__ done_cnt) {
    if (blockIdx.x == 0 && threadIdx.x == 0) *done_cnt = 0;
    int blk = blockIdx.x;
    int b = blk / (N_ / 16);
    int tile = blk % (N_ / 16);
    int tid = threadIdx.x;
    int n_local = tid & 15;
    int part = tid >> 4;              // 0..15

    __shared__ __align__(16) float pri[N_];
    __shared__ int cnt_sh[16][17];
    __shared__ int s_npos;
    if (tid == 0) s_npos = 0;
    __syncthreads();

    int lp = 0;
    for (int q = tid; q < N_; q += 256) {
        bool pos = d2w[b * N_ + q] < R2_;
        pri[q] = pos ? INFINITY : jax_uniform_r(b * N_ + q);
        if (pos) lp++;
    }
    atomicAdd(&s_npos, lp);
    __syncthreads();

    int n = tile * 16 + n_local;
    float ra = pri[n];

    int cnt = 0;
    const float4* p4 = reinterpret_cast<const float4*>(pri);
    for (int o = 0; o < 8; ++o) {
        float4 v[4];
#pragma unroll
        for (int k = 0; k < 4; ++k) v[k] = p4[part + (o * 4 + k) * 16];
#pragma unroll
        for (int k = 0; k < 4; ++k) {
            int qb = (part + (o * 4 + k) * 16) * 4;
            cnt += ((v[k].x < ra) || (v[k].x == ra && (qb + 0) < n)) ? 1 : 0;
            cnt += ((v[k].y < ra) || (v[k].y == ra && (qb + 1) < n)) ? 1 : 0;
            cnt += ((v[k].z < ra) || (v[k].z == ra && (qb + 2) < n)) ? 1 : 0;
            cnt += ((v[k].w < ra) || (v[k].w == ra && (qb + 3) < n)) ? 1 : 0;
        }
    }
    cnt_sh[part][n_local] = cnt;
    __syncthreads();

    if (tid < 16) {
        int tot = 0;
#pragma unroll
        for (int p = 0; p < 16; ++p) tot += cnt_sh[p][tid];
        int npos = s_npos;
        int kk = (npos > 0) ? npos : 2;
        int n2 = tile * 16 + tid;
        float r2 = pri[n2];
        selws[b * N_ + n2] = (r2 == INFINITY) ? 1.0f : ((tot < kk) ? 1.0f : 0.0f);
    }
}

// ---------------------------------------------------------------------------
// K3: ADD-S min. Grid = B*(N/8) = 1024 blocks (4/CU, 16 waves/CU).
// Block = 2 i-groups (4 i each) x 128 j-parts (16 contiguous j each).
// gg in two 16-float halves keeps live regs ~90; launch_bounds(256,4).
__global__ __launch_bounds__(256, 4) void adds_kernel(const float* __restrict__ Parr,
                                                      const float* __restrict__ Garr,
                                                      float* __restrict__ mOut) {
    int blk = blockIdx.x;
    int b = blk / (N_ / 8);
    int tile = blk % (N_ / 8);
    int ig = threadIdx.x & 1;              // 2 groups x 4 i
    int part = threadIdx.x >> 1;           // 0..127
    int i0 = tile * 8 + ig * 4;

    const float4* P4 = reinterpret_cast<const float4*>(Parr) + ((size_t)b * N_ + i0) * 4;
    float Pv[4][16];
#pragma unroll
    for (int ii = 0; ii < 4; ++ii) {
#pragma unroll
        for (int q = 0; q < 4; ++q) {
            float4 t4 = P4[ii * 4 + q];
            Pv[ii][q * 4 + 0] = t4.x; Pv[ii][q * 4 + 1] = t4.y;
            Pv[ii][q * 4 + 2] = t4.z; Pv[ii][q * 4 + 3] = t4.w;
        }
    }

    const float4* Gb4 = reinterpret_cast<const float4*>(Garr) + (size_t)b * N_ * 8;
    float best[4] = {INFINITY, INFINITY, INFINITY, INFINITY};
    int j0 = part * 16;
    for (int j = j0; j < j0 + 16; ++j) {
        const float4* G4 = Gb4 + (size_t)j * 8;
        float gg[16];
        // half 1: G
#pragma unroll
        for (int q = 0; q < 4; ++q) {
            float4 t4 = G4[q];
            gg[q * 4 + 0] = t4.x; gg[q * 4 + 1] = t4.y;
            gg[q * 4 + 2] = t4.z; gg[q * 4 + 3] = t4.w;
        }
        {
            float d[4] = {0.0f, 0.0f, 0.0f, 0.0f};
#pragma unroll
            for (int q = 0; q < 15; ++q)
#pragma unroll
                for (int ii = 0; ii < 4; ++ii) d[ii] += Pv[ii][q] * gg[q];
#pragma unroll
            for (int ii = 0; ii < 4; ++ii) {
                float s = Pv[ii][15] + gg[15] - 2.0f * d[ii];
                best[ii] = fminf(best[ii], s);
            }
        }
        // half 2: Gs
#pragma unroll
        for (int q = 0; q < 4; ++q) {
            float4 t4 = G4[4 + q];
            gg[q * 4 + 0] = t4.x; gg[q * 4 + 1] = t4.y;
            gg[q * 4 + 2] = t4.z; gg[q * 4 + 3] = t4.w;
        }
        {
            float d[4] = {0.0f, 0.0f, 0.0f, 0.0f};
#pragma unroll
            for (int q = 0; q < 15; ++q)
#pragma unroll
                for (int ii = 0; ii < 4; ++ii) d[ii] += Pv[ii][q] * gg[q];
#pragma unroll
            for (int ii = 0; ii < 4; ++ii) {
                float s = Pv[ii][15] + gg[15] - 2.0f * d[ii];
                best[ii] = fminf(best[ii], s);
            }
        }
    }
    __shared__ float sm[128][9];
#pragma unroll
    for (int ii = 0; ii < 4; ++ii) sm[part][ig * 4 + ii] = best[ii];
    __syncthreads();
    if (threadIdx.x < 8) {
        float bb = sm[0][threadIdx.x];
#pragma unroll
        for (int q = 1; q < 128; ++q) bb = fminf(bb, sm[q][threadIdx.x]);
        mOut[b * N_ + tile * 8 + threadIdx.x] = bb;
    }
}

// ---------------------------------------------------------------------------
// K4: per-batch sums, parallelized. Grid = B*8 = 32 blocks, 1 n per thread.
// Fixed-order partials + last-block deterministic combine.
__global__ __launch_bounds__(256) void finalize_kernel(
        const float* __restrict__ scores, const float* __restrict__ gwh,
        const float* __restrict__ pcw, const int* __restrict__ idxw,
        const float* __restrict__ d2w, const float* __restrict__ mw,
        const float* __restrict__ selws,
        float* __restrict__ partials, int* __restrict__ done_cnt,
        float* __restrict__ out) {
    int blk = blockIdx.x;                  // B*8
    int b = blk >> 3;
    int part = blk & 7;
    int tid = threadIdx.x;
    int n = part * 256 + tid;
    __shared__ float wsum[4][5];

    float sc = scores[b * N_ + n];
    float pcl = fminf(fmaxf(sc, EPS_), 0.9999999f);
    bool pos = d2w[b * N_ + n] < R2_;
    float s = pos ? 1.0f : 0.0f;
    float bce = -(s * logf(pcl) + (1.0f - s) * logf(1.0f - pcl));
    float selv = selws[b * N_ + n];
    float sum_sel = selv;
    float sum_bce = bce * selv;
    float sum_pos = s;
    float sum_wl = 0.0f, sum_adds = 0.0f;
    if (pos) {
        int jx = idxw[b * N_ + n];
        float w = pcw[b * M_ + jx];
        float acc = 0.0f;
#pragma unroll
        for (int jb = 0; jb < 10; ++jb) {
            float x = gwh[((size_t)b * 10 + jb) * N_ + n];
            float mh = (w >= c_LO[jb] && w < c_HI[jb]) ? 1.0f : 0.0f;
            float bw = fmaxf(x, 0.0f) - x * mh + log1pf(expf(-fabsf(x)));
            acc += c_BW[jb] * bw;
        }
        sum_wl = acc * 0.1f;
        float mv = mw[b * N_ + n];
        sum_adds = sc * sqrtf(fmaxf(mv, 0.0f) + 1e-12f);
    }

    // deterministic reduce: wave shuffle + per-wave LDS + thread-0 combine
    float v0 = sum_sel, v1 = sum_bce, v2 = sum_wl, v3 = sum_adds, v4 = sum_pos;
#pragma unroll
    for (int off = 32; off > 0; off >>= 1) {
        v0 += __shfl_down(v0, off);
        v1 += __shfl_down(v1, off);
        v2 += __shfl_down(v2, off);
        v3 += __shfl_down(v3, off);
        v4 += __shfl_down(v4, off);
    }
    int wv = tid >> 6, lane = tid & 63;
    if (lane == 0) {
        wsum[wv][0] = v0; wsum[wv][1] = v1; wsum[wv][2] = v2; wsum[wv][3] = v3; wsum[wv][4] = v4;
    }
    __syncthreads();
    if (tid == 0) {
        float t0 = 0, t1 = 0, t2 = 0, t3 = 0, t4 = 0;
#pragma unroll
        for (int w = 0; w < 4; ++w) {
            t0 += wsum[w][0]; t1 += wsum[w][1]; t2 += wsum[w][2]; t3 += wsum[w][3]; t4 += wsum[w][4];
        }
        float* pp = partials + (size_t)blk * 5;
        pp[0] = t0; pp[1] = t1; pp[2] = t2; pp[3] = t3; pp[4] = t4;
        __threadfence();
        int old = atomicAdd(done_cnt, 1);
        if (old == B_ * 8 - 1) {
            __threadfence();
            float bin = 0, wid = 0, ad = 0;
#pragma unroll
            for (int b2 = 0; b2 < B_; ++b2) {
                float u0 = 0, u1 = 0, u2 = 0, u3 = 0, u4 = 0;
#pragma unroll
                for (int p2 = 0; p2 < 8; ++p2) {       // fixed order: deterministic
                    const float* q = partials + (size_t)(b2 * 8 + p2) * 5;
                    u0 += q[0]; u1 += q[1]; u2 += q[2]; u3 += q[3]; u4 += q[4];
                }
                float piv = fmaxf(u4, 1.0f);           // pos_in_view
                bin += u1 / fmaxf(u0, 1.0f);
                wid += u2 / piv;
                ad  += u3 / piv;
            }
            bin *= 0.25f; wid *= 0.25f; ad *= 0.25f;
            out[0] = bin + wid + 3.0f * ad;
            out[1] = bin;
            out[2] = wid;
            out[3] = ad;
        }
    }
}

// ---------------------------------------------------------------------------
extern "C" void kernel_launch(void* const* d_in, const int* in_sizes, int n_in,
                              void* d_out, int out_size, void* d_ws, size_t ws_size,
                              hipStream_t stream) {
    const float* pred_grasps = (const float*)d_in[0];   // (4,2048,4,4)
    const float* pred_scores = (const float*)d_in[1];   // (4,2048,1)
    const float* pred_points = (const float*)d_in[2];   // (4,2048,3)
    const float* gwh         = (const float*)d_in[3];   // (4,10,2048)
    const float* pcp         = (const float*)d_in[4];   // (4,4096,3)
    const float* pcw         = (const float*)d_in[5];   // (4,4096)
    const float* pcr         = (const float*)d_in[6];   // (4,4096,3,3)
    const float* pct         = (const float*)d_in[7];   // (4,4096,3)
    const float* cp          = (const float*)d_in[8];   // (1,5,3)
    const float* cps         = (const float*)d_in[9];   // (1,5,3)
    (void)in_sizes; (void)n_in; (void)out_size; (void)ws_size;

    float* ws = (float*)d_ws;
    int*   idxw  = (int*)ws;                            //   8192
    float* d2w   = ws + 8192;                           //   8192
    float* Pw    = ws + 16384;                          // 131072
    float* Gw    = Pw + 131072;                         // 262144
    float* mw    = Gw + 262144;                         //   8192
    float* selws = mw + 8192;                           //   8192
    float* parts = selws + 8192;                        //    160
    int*   done  = (int*)(parts + 160);                 //      1
    float* outp  = (float*)d_out;

    hipLaunchKernelGGL(nn_prep_kernel, dim3(B_ * (N_ / 8)), dim3(256), 0, stream,
                       pred_points, pcp, pred_grasps, pcr, pct, cp, cps,
                       idxw, d2w, Pw, Gw);
    hipLaunchKernelGGL(rank_kernel, dim3(B_ * (N_ / 16)), dim3(256), 0, stream,
                       d2w, selws, done);
    hipLaunchKernelGGL(adds_kernel, dim3(B_ * (N_ / 8)), dim3(256), 0, stream,
                       Pw, Gw, mw);
    hipLaunchKernelGGL(finalize_kernel, dim3(B_ * 8), dim3(256), 0, stream,
                       pred_scores, gwh, pcw, idxw, d2w, mw, selws, parts, done, outp);
}